// Round 1
// baseline (129.004 us; speedup 1.0000x reference)
//
#include <hip/hip_runtime.h>
#include <hip/hip_bf16.h>

// Problem constants (from reference): N=20000, K=32, D=128
#define NN 20000
#define KK 32
#define DD 128

// ---------------------------------------------------------------------------
// Kernel 0: fold a_w through W1/W2 once.
//   v1[d] = sum_e a_w[e] * W1[e*D + d]   (row-vector times matrix)
//   v2[d] = sum_e a_w[e] * W2[e*D + d]
// ws layout (floats): [0..127]=v1, [128..255]=v2, [256]=a_b
// ---------------------------------------------------------------------------
__global__ __launch_bounds__(DD) void fold_weights_kernel(
    const float* __restrict__ W1, const float* __restrict__ W2,
    const float* __restrict__ a_w, const float* __restrict__ a_b,
    float* __restrict__ ws) {
  const int d = threadIdx.x;  // 0..127
  float s1 = 0.f, s2 = 0.f;
#pragma unroll 8
  for (int e = 0; e < DD; ++e) {
    const float aw = a_w[e];
    s1 += aw * W1[e * DD + d];   // coalesced across d
    s2 += aw * W2[e * DD + d];
  }
  ws[d] = s1;
  ws[DD + d] = s2;
  if (d == 0) ws[2 * DD] = a_b[0];
}

// ---------------------------------------------------------------------------
// Kernel 1: one block (256 threads = 4 waves) per node.
//   scores[k] = tanh(nk[n]·v1 + mk[n,k]·v2 + b) ; coef = softmax_k ; out = coef·mv
// Thread t: f = t&31 (float4 index over D), kg = t>>5 (neighbor group 0..7).
// A wave's loads cover two fully contiguous 512B rows -> perfect coalescing.
// ---------------------------------------------------------------------------
__global__ __launch_bounds__(256) void attn_agg_kernel(
    const float* __restrict__ mk, const float* __restrict__ nk,
    const float* __restrict__ mv, const float* __restrict__ ws,
    float* __restrict__ out) {
  const int n = blockIdx.x;
  const int t = threadIdx.x;
  const int f = t & 31;    // which float4 of the 128-dim vector
  const int kg = t >> 5;   // neighbor group (0..7)

  __shared__ float s_scores[KK];
  __shared__ float s_coef[KK];
  __shared__ float s_center;
  __shared__ float4 s_part[4][32];

  const float4* v2p = (const float4*)(ws + DD);
  const float4 w2 = v2p[f];

  // ---- center dot: nk[n] · v1, by lanes 0..31 of wave 0 ----
  if (t < 32) {
    const float4 a = ((const float4*)(nk + (size_t)n * DD))[t];
    const float4 b = ((const float4*)ws)[t];
    float c = a.x * b.x + a.y * b.y + a.z * b.z + a.w * b.w;
#pragma unroll
    for (int o = 16; o >= 1; o >>= 1) c += __shfl_xor(c, o, 64);
    if (t == 0) s_center = c;
  }

  // ---- neighbor dots: mk[n,k] · v2 ----
  const float4* mkp = (const float4*)(mk + (size_t)n * KK * DD);
  float dj[4];
#pragma unroll
  for (int j = 0; j < 4; ++j) {
    const int k = kg + 8 * j;
    const float4 a = mkp[k * (DD / 4) + f];
    dj[j] = a.x * w2.x + a.y * w2.y + a.z * w2.z + a.w * w2.w;
  }
#pragma unroll
  for (int j = 0; j < 4; ++j) {
    float v = dj[j];
#pragma unroll
    for (int o = 16; o >= 1; o >>= 1) v += __shfl_xor(v, o, 64);
    if (f == 0) s_scores[kg + 8 * j] = v;
  }
  __syncthreads();

  // ---- softmax over 32 neighbors (tanh in [-1,1] -> no max-shift needed) ----
  if (t < 32) {
    const float b = ws[2 * DD];
    const float s = tanhf(s_scores[t] + s_center + b);
    const float e = expf(s);
    float sum = e;
#pragma unroll
    for (int o = 16; o >= 1; o >>= 1) sum += __shfl_xor(sum, o, 64);
    s_coef[t] = e / sum;
  }
  __syncthreads();

  // ---- weighted sum of middle_value ----
  const float4* mvp = (const float4*)(mv + (size_t)n * KK * DD);
  float4 acc = make_float4(0.f, 0.f, 0.f, 0.f);
#pragma unroll
  for (int j = 0; j < 4; ++j) {
    const int k = kg + 8 * j;
    const float c = s_coef[k];
    const float4 v = mvp[k * (DD / 4) + f];
    acc.x += c * v.x;
    acc.y += c * v.y;
    acc.z += c * v.z;
    acc.w += c * v.w;
  }
  // combine the two neighbor-groups living in the same wave
  acc.x += __shfl_xor(acc.x, 32, 64);
  acc.y += __shfl_xor(acc.y, 32, 64);
  acc.z += __shfl_xor(acc.z, 32, 64);
  acc.w += __shfl_xor(acc.w, 32, 64);

  const int w = t >> 6;  // wave id
  if ((t & 63) < 32) s_part[w][f] = acc;
  __syncthreads();

  if (t < 32) {
    float4 r = s_part[0][t];
    const float4 r1 = s_part[1][t];
    const float4 r2 = s_part[2][t];
    const float4 r3 = s_part[3][t];
    r.x += r1.x + r2.x + r3.x;
    r.y += r1.y + r2.y + r3.y;
    r.z += r1.z + r2.z + r3.z;
    r.w += r1.w + r2.w + r3.w;
    ((float4*)(out + (size_t)n * DD))[t] = r;
  }
}

extern "C" void kernel_launch(void* const* d_in, const int* in_sizes, int n_in,
                              void* d_out, int out_size, void* d_ws, size_t ws_size,
                              hipStream_t stream) {
  const float* middle_key = (const float*)d_in[0];
  const float* nodes_key = (const float*)d_in[1];
  const float* middle_value = (const float*)d_in[2];
  const float* W1 = (const float*)d_in[3];
  const float* W2 = (const float*)d_in[4];
  const float* a_w = (const float*)d_in[5];
  const float* a_b = (const float*)d_in[6];
  float* out = (float*)d_out;
  float* ws = (float*)d_ws;

  fold_weights_kernel<<<1, DD, 0, stream>>>(W1, W2, a_w, a_b, ws);
  attn_agg_kernel<<<NN, 256, 0, stream>>>(middle_key, nodes_key, middle_value,
                                          ws, out);
}

// Round 2
// 110.071 us; speedup vs baseline: 1.1720x; 1.1720x over previous
//
#include <hip/hip_runtime.h>
#include <hip/hip_bf16.h>

// Problem constants (from reference): N=20000, K=32, D=128
#define NN 20000
#define KK 32
#define DD 128

typedef float f4 __attribute__((ext_vector_type(4)));

// ---------------------------------------------------------------------------
// Kernel 0: fold a_w through W1/W2 once.
//   v1[d] = sum_e a_w[e] * W1[e*D + d]
//   v2[d] = sum_e a_w[e] * W2[e*D + d]
// ws layout (floats): [0..127]=v1, [128..255]=v2, [256]=a_b
// ---------------------------------------------------------------------------
__global__ __launch_bounds__(DD) void fold_weights_kernel(
    const float* __restrict__ W1, const float* __restrict__ W2,
    const float* __restrict__ a_w, const float* __restrict__ a_b,
    float* __restrict__ ws) {
  const int d = threadIdx.x;  // 0..127
  float s1 = 0.f, s2 = 0.f;
#pragma unroll 8
  for (int e = 0; e < DD; ++e) {
    const float aw = a_w[e];
    s1 += aw * W1[e * DD + d];   // coalesced across d
    s2 += aw * W2[e * DD + d];
  }
  ws[d] = s1;
  ws[DD + d] = s2;
  if (d == 0) ws[2 * DD] = a_b[0];
}

// ---------------------------------------------------------------------------
// Kernel 1: one block (256 threads = 4 waves) per node.
// Thread t: f = t&31 (float4 index over D), kg = t>>5 (neighbor group 0..7).
// ALL global loads (mk AND mv) are issued before any reduce/barrier so both
// 16KB streams are in flight while scores/softmax compute. Softmax is done
// redundantly per wave (lane owns k = t&31) -> only 2 barriers total.
// ---------------------------------------------------------------------------
__global__ __launch_bounds__(256) void attn_agg_kernel(
    const float* __restrict__ mk, const float* __restrict__ nk,
    const float* __restrict__ mv, const float* __restrict__ ws,
    float* __restrict__ out) {
  const int n = blockIdx.x;
  const int t = threadIdx.x;
  const int f = t & 31;    // which float4 of the 128-dim vector
  const int kg = t >> 5;   // neighbor group (0..7)

  __shared__ float s_scores[KK];
  __shared__ float s_center;
  __shared__ f4 s_part[4][32];

  const f4* mkp = (const f4*)(mk + (size_t)n * KK * DD);
  const f4* mvp = (const f4*)(mv + (size_t)n * KK * DD);

  // ---- issue ALL global loads up front (mv does not depend on coef) ----
  f4 ak[4], av[4];
#pragma unroll
  for (int j = 0; j < 4; ++j) {
    const int k = kg + 8 * j;
    ak[j] = __builtin_nontemporal_load(mkp + k * (DD / 4) + f);
    av[j] = __builtin_nontemporal_load(mvp + k * (DD / 4) + f);
  }

  const f4 w2 = ((const f4*)(ws + DD))[f];

  // ---- center dot: nk[n] · v1, by lanes 0..31 of wave 0 ----
  if (t < 32) {
    const f4 a = __builtin_nontemporal_load((const f4*)(nk + (size_t)n * DD) + t);
    const f4 b = ((const f4*)ws)[t];
    const f4 m = a * b;
    float c = m[0] + m[1] + m[2] + m[3];
#pragma unroll
    for (int o = 16; o >= 1; o >>= 1) c += __shfl_xor(c, o, 64);
    if (t == 0) s_center = c;
  }

  // ---- neighbor dots: mk[n,k] · v2, reduce over the 32 f-lanes ----
#pragma unroll
  for (int j = 0; j < 4; ++j) {
    const f4 m = ak[j] * w2;
    float v = m[0] + m[1] + m[2] + m[3];
#pragma unroll
    for (int o = 16; o >= 1; o >>= 1) v += __shfl_xor(v, o, 64);
    if (f == 0) s_scores[kg + 8 * j] = v;  // lanes 0 and 32 of each wave
  }
  __syncthreads();

  // ---- softmax over 32 neighbors, redundantly in every wave ----
  // (tanh in [-1,1] -> no max-shift needed for exp stability)
  const float bias = ws[2 * DD];
  const float ctr = s_center;
  const float sc = tanhf(s_scores[f] + ctr + bias);   // lane owns k = f
  const float e = expf(sc);
  float sum = e;
#pragma unroll
  for (int o = 16; o >= 1; o >>= 1) sum += __shfl_xor(sum, o, 64);
  const float inv = 1.f / sum;   // wave-uniform

  // ---- weighted sum of middle_value (registers already loaded) ----
  f4 acc = {0.f, 0.f, 0.f, 0.f};
#pragma unroll
  for (int j = 0; j < 4; ++j) {
    const float cj = __shfl(e, kg + 8 * j, 64) * inv;  // coef[k] from lane k
    acc += cj * av[j];
  }
  // combine the two neighbor-groups living in the same wave
  acc[0] += __shfl_xor(acc[0], 32, 64);
  acc[1] += __shfl_xor(acc[1], 32, 64);
  acc[2] += __shfl_xor(acc[2], 32, 64);
  acc[3] += __shfl_xor(acc[3], 32, 64);

  const int w = t >> 6;  // wave id
  if ((t & 63) < 32) s_part[w][f] = acc;
  __syncthreads();

  if (t < 32) {
    const f4 r = s_part[0][t] + s_part[1][t] + s_part[2][t] + s_part[3][t];
    __builtin_nontemporal_store(r, (f4*)(out + (size_t)n * DD) + t);
  }
}

extern "C" void kernel_launch(void* const* d_in, const int* in_sizes, int n_in,
                              void* d_out, int out_size, void* d_ws, size_t ws_size,
                              hipStream_t stream) {
  const float* middle_key = (const float*)d_in[0];
  const float* nodes_key = (const float*)d_in[1];
  const float* middle_value = (const float*)d_in[2];
  const float* W1 = (const float*)d_in[3];
  const float* W2 = (const float*)d_in[4];
  const float* a_w = (const float*)d_in[5];
  const float* a_b = (const float*)d_in[6];
  float* out = (float*)d_out;
  float* ws = (float*)d_ws;

  fold_weights_kernel<<<1, DD, 0, stream>>>(W1, W2, a_w, a_b, ws);
  attn_agg_kernel<<<NN, 256, 0, stream>>>(middle_key, nodes_key, middle_value,
                                          ws, out);
}